// Round 9
// baseline (3975.090 us; speedup 1.0000x reference)
//
#include <hip/hip_runtime.h>
#include <cstdint>

typedef __attribute__((ext_vector_type(8))) short short8;
typedef __attribute__((ext_vector_type(4))) short s4v;
typedef __attribute__((ext_vector_type(4))) float floatx4;

#define DEV __device__ __forceinline__

DEV short f2bf(float f) {
  unsigned u = __builtin_bit_cast(unsigned, f);
  u += 0x7fffu + ((u >> 16) & 1u);
  return (short)(u >> 16);
}
DEV short f2bf_ru(float f) {
  unsigned u = __builtin_bit_cast(unsigned, f);
  return (short)((u + 0x8000u) >> 16);
}
DEV float bf2f(short s) {
  unsigned u = ((unsigned)(unsigned short)s) << 16;
  return __builtin_bit_cast(float, u);
}
DEV float gelu_exact(float x) {
  return 0.5f * x * (1.0f + erff(x * 0.70710678118654752f));
}
DEV float gelu_fast(float x) {
  const float t2 = 1.5957691216057308f * (x + 0.044715f * x * x * x);
  return x / (1.0f + __expf(-t2));
}
DEV void gload16(const void* g, void* l) {
  __builtin_amdgcn_global_load_lds((const __attribute__((address_space(1))) void*)g,
                                   (__attribute__((address_space(3))) void*)l,
                                   16, 0, 0);
}

// ---------------------------------------------------------------------------
// 128x128-tile bf16 MFMA GEMM, swapped-operand epilogue.
// MODE 0: C = v + bias (row-major ldc)
// MODE 1: gelu(v + bias)
// MODE 2: v + bias + pe[(row&127)*384 + col]
// MODE 3: v + bias, head-major store: col -> g=col/48,d=col%48;
//         dest = C + g*hstride + row*48 + d
// ---------------------------------------------------------------------------
template<int MODE>
__global__ __launch_bounds__(256)
void gemm_kernel(const short* __restrict__ A, const short* __restrict__ Bw,
                 const float* __restrict__ bias, short* __restrict__ C,
                 const float* __restrict__ pe,
                 int K, int lda, int ldb, int ldc, int Nstore, int NT, long hstride)
{
  __shared__ __align__(16) short lds[128 * 136];
  short* As = lds;
  short* Bs = lds + 128 * 32;
  short* Ct = lds;

  const int tid  = threadIdx.x;
  const int wave = tid >> 6, lane = tid & 63;
  const int quad = lane >> 4, r16 = lane & 15;
  const int per = gridDim.x >> 3;
  const int gti = (blockIdx.x & 7) * per + (blockIdx.x >> 3);
  const int mt = gti / NT, nt = gti - mt * NT;
  const int wm = (wave >> 1) * 64, wn = (wave & 1) * 64;

  const long Abase = (long)mt * 128 * lda;
  const long Bbase = (long)nt * 128 * ldb;

  const int row0 = tid >> 2,         cc0 = (tid & 3) ^ ((row0 >> 1) & 3);
  const int row1 = (256 + tid) >> 2, cc1 = ((256 + tid) & 3) ^ ((row1 >> 1) & 3);

  floatx4 acc[4][4] = {};

  for (int k0 = 0; k0 < K; k0 += 32) {
    __syncthreads();
    gload16(A  + Abase + (long)row0 * lda + k0 + cc0 * 8, &As[(0 * 256 + wave * 64) * 8]);
    gload16(A  + Abase + (long)row1 * lda + k0 + cc1 * 8, &As[(1 * 256 + wave * 64) * 8]);
    gload16(Bw + Bbase + (long)row0 * ldb + k0 + cc0 * 8, &Bs[(0 * 256 + wave * 64) * 8]);
    gload16(Bw + Bbase + (long)row1 * ldb + k0 + cc1 * 8, &Bs[(1 * 256 + wave * 64) * 8]);
    __syncthreads();

    short8 af[4], bfr[4];
#pragma unroll
    for (int i = 0; i < 4; ++i) {
      const int R = wm + i * 16 + r16;
      af[i] = *(const short8*)&As[R * 32 + (quad ^ ((R >> 1) & 3)) * 8];
    }
#pragma unroll
    for (int j = 0; j < 4; ++j) {
      const int R = wn + j * 16 + r16;
      bfr[j] = *(const short8*)&Bs[R * 32 + (quad ^ ((R >> 1) & 3)) * 8];
    }
#pragma unroll
    for (int i = 0; i < 4; ++i)
#pragma unroll
      for (int j = 0; j < 4; ++j)
        acc[i][j] = __builtin_amdgcn_mfma_f32_16x16x32_bf16(bfr[j], af[i], acc[i][j], 0, 0, 0);
  }

  const int mb0 = mt * 128, tb = nt * 128;

  __syncthreads();
#pragma unroll
  for (int j = 0; j < 4; ++j) {
    const int n0 = wn + j * 16 + quad * 4;
    const floatx4 b4 = *(const floatx4*)&bias[tb + n0];
#pragma unroll
    for (int i = 0; i < 4; ++i) {
      const int m = wm + i * 16 + r16;
      floatx4 v = acc[i][j] + b4;
      if (MODE == 1) {
#pragma unroll
        for (int rg = 0; rg < 4; ++rg) v[rg] = gelu_fast(v[rg]);
      }
      if (MODE == 2) {
        const floatx4 p4 = *(const floatx4*)&pe[((mb0 + m) & 127) * 384 + tb + n0];
        v = v + p4;
      }
      s4v o4;
#pragma unroll
      for (int rg = 0; rg < 4; ++rg) o4[rg] = f2bf_ru(v[rg]);
      *(s4v*)&Ct[m * 136 + n0] = o4;
    }
  }
  __syncthreads();

#pragma unroll
  for (int rr = 0; rr < 8; ++rr) {
    const int chunk = rr * 256 + tid;
    const int row = chunk >> 4, ch = chunk & 15;
    const int gcol = tb + ch * 8;
    if (MODE == 3) {
      const int g = gcol / 48, d0 = gcol - g * 48;
      *(short8*)(C + (long)g * hstride + (long)(mb0 + row) * 48 + d0) =
          *(const short8*)&Ct[row * 136 + ch * 8];
    } else if (gcol < Nstore) {
      *(short8*)(C + (long)(mb0 + row) * ldc + gcol) = *(const short8*)&Ct[row * 136 + ch * 8];
    }
  }
}

// ---------------------------------------------------------------------------
// Fused GEMM + residual + LayerNorm, N=288 exact.  M-tile 128, 512 threads.
// AHEAD: A is head-major [g][Mrows][48] with section stride ahs (Wo case).
// ---------------------------------------------------------------------------
template<bool AHEAD>
__global__ __launch_bounds__(512, 4)
void gemm_ln_kernel(const short* __restrict__ A, const short* __restrict__ Bw,
                    const float* __restrict__ bias, short* __restrict__ h,
                    const float* __restrict__ lnw, const float* __restrict__ lnb,
                    const float* __restrict__ skip_p, int layer, int use_skip,
                    int K, int lda, int ldb, long ahs)
{
  __shared__ __align__(16) short lds[128 * 296];
  short* As = lds;                 // [128][32]
  short* Bs = lds + 128 * 32;      // [288][32]
  short* Hs = lds;                 // [128][296]

  const int tid  = threadIdx.x;
  const int wave = tid >> 6, lane = tid & 63;
  const int quad = lane >> 4, r16 = lane & 15;
  const int mt = blockIdx.x;
  const long mrow0 = (long)mt * 128;

  floatx4 acc[18] = {};

  for (int k0 = 0; k0 < K; k0 += 32) {
    __syncthreads();
    for (int c = tid; c < 1664; c += 512) {
      const void* src;
      if (c < 512) {
        const int row = c >> 2, cc = (c & 3) ^ ((row >> 1) & 3);
        if (AHEAD) {
          const int kc = k0 + cc * 8;
          const int g = kc / 48, d = kc - g * 48;
          src = A + (long)g * ahs + (mrow0 + row) * 48 + d;
        } else {
          src = A + (mrow0 + row) * lda + k0 + cc * 8;
        }
      } else {
        const int cb = c - 512;
        const int row = cb >> 2, cc = (cb & 3) ^ ((row >> 1) & 3);
        src = Bw + (long)row * ldb + k0 + cc * 8;
      }
      gload16(src, &lds[(size_t)(c & ~63) * 8]);
    }
    __syncthreads();

    const int Ra = wave * 16 + r16;
    const short8 af = *(const short8*)&As[Ra * 32 + (quad ^ ((Ra >> 1) & 3)) * 8];
#pragma unroll
    for (int t = 0; t < 18; ++t) {
      const int Rb = t * 16 + r16;
      const short8 bfr = *(const short8*)&Bs[Rb * 32 + (quad ^ ((Rb >> 1) & 3)) * 8];
      acc[t] = __builtin_amdgcn_mfma_f32_16x16x32_bf16(bfr, af, acc[t], 0, 0, 0);
    }
  }

  __syncthreads();
  for (int c = tid; c < 4608; c += 512) {
    const int row = c / 36, ch = c - row * 36;
    *(short8*)&Hs[row * 296 + ch * 8] =
        *(const short8*)(h + (mrow0 + row) * 288 + ch * 8);
  }
  __syncthreads();

  const float skipv = use_skip ? skip_p[layer] : 1.0f;
  const int m = wave * 16 + r16;

  float ps = 0.f, pss = 0.f;
#pragma unroll
  for (int t = 0; t < 18; ++t) {
    const int n0 = t * 16 + quad * 4;
    const floatx4 b4 = *(const floatx4*)&bias[n0];
    const s4v h4 = *(const s4v*)&Hs[m * 296 + n0];
#pragma unroll
    for (int rg = 0; rg < 4; ++rg) {
      const float y = bf2f(h4[rg]) + skipv * (acc[t][rg] + b4[rg]);
      acc[t][rg] = y;
      ps += y; pss += y * y;
    }
  }
  ps  += __shfl_xor(ps, 16);  ps  += __shfl_xor(ps, 32);
  pss += __shfl_xor(pss, 16); pss += __shfl_xor(pss, 32);
  const float mean = ps * (1.f / 288.f);
  const float var  = pss * (1.f / 288.f) - mean * mean;
  const float rstd = rsqrtf(var + 1e-5f);

#pragma unroll
  for (int t = 0; t < 18; ++t) {
    const int n0 = t * 16 + quad * 4;
    const floatx4 w4 = *(const floatx4*)&lnw[n0];
    const floatx4 l4 = *(const floatx4*)&lnb[n0];
    s4v o4;
#pragma unroll
    for (int rg = 0; rg < 4; ++rg)
      o4[rg] = f2bf_ru((acc[t][rg] - mean) * rstd * w4[rg] + l4[rg]);
    *(s4v*)&Hs[m * 296 + n0] = o4;
  }
  __syncthreads();

  for (int c = tid; c < 4608; c += 512) {
    const int row = c / 36, ch = c - row * 36;
    *(short8*)(h + (mrow0 + row) * 288 + ch * 8) =
        *(const short8*)&Hs[row * 296 + ch * 8];
  }
}

// ---------------------------------------------------------------------------
// Attention.  qkv head-major [24][Mc][48]: q = g 0..7, k = 8..15, v = 16..23.
// Coalesced section reads; o overwrites the v-section (race-free: block (b,h)
// is the sole reader/writer of g=16+h rows b*128..+127, v LDS-staged first).
// vsT: 48 rows, bank-skewed; on=32 waves skip the discarded j=1 tile.
// ---------------------------------------------------------------------------
__global__ __launch_bounds__(256)
void attn_kernel(short* __restrict__ qkv,
                 const float* __restrict__ temp, const float* __restrict__ qscale,
                 int layer, long Mc)
{
  __shared__ __align__(16) short qk[2 * 128 * 72];   // qs|ks, later Pb[128][136]
  __shared__ __align__(16) short vsT[48 * 136 + 32]; // [d][s], skew ((d>>3)&3)*8
  __shared__ float red[2][2][64];

  short* qs = qk;
  short* ks = qk + 128 * 72;
  short* Pb = qk;

  const int b = blockIdx.x, h = blockIdx.y;
  const int tid = threadIdx.x;
  const long sec = Mc * 48;
  const short* qg = qkv + (long)h * sec + (long)b * 128 * 48;
  const short* kg = qg + 8 * sec;
  const short* vg = qg + 16 * sec;
  short* og = qkv + (long)(16 + h) * sec + (long)b * 128 * 48;

  // coalesced q,k loads (96 B rows)
  for (int c = tid; c < 768; c += 256) {
    const int s = c / 6, dc = c - (c / 6) * 6;
    *(short8*)&qs[s * 72 + dc * 8] = *(const short8*)(qg + (long)s * 48 + dc * 8);
    *(short8*)&ks[s * 72 + dc * 8] = *(const short8*)(kg + (long)s * 48 + dc * 8);
  }
  // zero pad cols 48..71
  {
    short8 z;
#pragma unroll
    for (int j = 0; j < 8; ++j) z[j] = 0;
    for (int c = tid; c < 384; c += 256) {
      const int s = c / 3, t = c - (c / 3) * 3;
      *(short8*)&qs[s * 72 + 48 + t * 8] = z;
      *(short8*)&ks[s * 72 + 48 + t * 8] = z;
    }
  }
  // v transposed into vsT[d][s] with bank skew
  for (int c = tid; c < 768; c += 256) {
    const int s = c / 6, dc = c - (c / 6) * 6;
    const short8 tv = *(const short8*)(vg + (long)s * 48 + dc * 8);
#pragma unroll
    for (int j = 0; j < 8; ++j) {
      const int row = dc * 8 + j;
      vsT[row * 136 + ((row >> 3) & 3) * 8 + s] = tv[j];
    }
  }
  __syncthreads();

  const int wave = tid >> 6, lane = tid & 63;
  const int quad = lane >> 4, r16 = lane & 15;
  const int wm = (wave >> 1) * 64, wn = (wave & 1) * 64;
  const int rh = wave >> 1, ch = wave & 1;
  const float invs = 1.0f / (6.4031242374328485f * temp[layer]);
  const float qsc  = qscale[layer * 8 + h];

  floatx4 acc[4][4] = {};
#pragma unroll
  for (int kk = 0; kk < 2; ++kk) {
    const int k0 = kk * 32;
    short8 af[4], bfr[4];
#pragma unroll
    for (int i = 0; i < 4; ++i)
      af[i] = *(const short8*)&qs[(wm + i * 16 + r16) * 72 + k0 + quad * 8];
#pragma unroll
    for (int j = 0; j < 4; ++j)
      bfr[j] = *(const short8*)&ks[(wn + j * 16 + r16) * 72 + k0 + quad * 8];
#pragma unroll
    for (int i = 0; i < 4; ++i)
#pragma unroll
      for (int j = 0; j < 4; ++j)
        acc[i][j] = __builtin_amdgcn_mfma_f32_16x16x32_bf16(af[i], bfr[j], acc[i][j], 0, 0, 0);
  }
#pragma unroll
  for (int i = 0; i < 4; ++i)
#pragma unroll
    for (int j = 0; j < 4; ++j)
#pragma unroll
      for (int rg = 0; rg < 4; ++rg)
        acc[i][j][rg] *= invs;

  float rmax[4][4];
#pragma unroll
  for (int i = 0; i < 4; ++i)
#pragma unroll
    for (int rg = 0; rg < 4; ++rg) {
      float m = acc[i][0][rg];
#pragma unroll
      for (int j = 1; j < 4; ++j) m = fmaxf(m, acc[i][j][rg]);
      rmax[i][rg] = m;
    }
#pragma unroll
  for (int msk = 1; msk < 16; msk <<= 1)
#pragma unroll
    for (int i = 0; i < 4; ++i)
#pragma unroll
      for (int rg = 0; rg < 4; ++rg)
        rmax[i][rg] = fmaxf(rmax[i][rg], __shfl_xor(rmax[i][rg], msk));
  if (r16 == 0)
#pragma unroll
    for (int i = 0; i < 4; ++i)
#pragma unroll
      for (int rg = 0; rg < 4; ++rg)
        red[rh][ch][i * 16 + quad * 4 + rg] = rmax[i][rg];
  __syncthreads();
#pragma unroll
  for (int i = 0; i < 4; ++i)
#pragma unroll
    for (int rg = 0; rg < 4; ++rg) {
      const int r = i * 16 + quad * 4 + rg;
      rmax[i][rg] = fmaxf(red[rh][0][r], red[rh][1][r]);
    }

  float rsum[4][4] = {};
#pragma unroll
  for (int i = 0; i < 4; ++i)
#pragma unroll
    for (int j = 0; j < 4; ++j)
#pragma unroll
      for (int rg = 0; rg < 4; ++rg) {
        const float e = __expf(acc[i][j][rg] - rmax[i][rg]);
        acc[i][j][rg] = e;
        rsum[i][rg] += e;
      }
#pragma unroll
  for (int msk = 1; msk < 16; msk <<= 1)
#pragma unroll
    for (int i = 0; i < 4; ++i)
#pragma unroll
      for (int rg = 0; rg < 4; ++rg)
        rsum[i][rg] += __shfl_xor(rsum[i][rg], msk);
  __syncthreads();
  if (r16 == 0)
#pragma unroll
    for (int i = 0; i < 4; ++i)
#pragma unroll
      for (int rg = 0; rg < 4; ++rg)
        red[rh][ch][i * 16 + quad * 4 + rg] = rsum[i][rg];
  __syncthreads();
#pragma unroll
  for (int i = 0; i < 4; ++i)
#pragma unroll
    for (int rg = 0; rg < 4; ++rg) {
      const int r = i * 16 + quad * 4 + rg;
      rmax[i][rg] = qsc / (red[rh][0][r] + red[rh][1][r]);
    }

#pragma unroll
  for (int i = 0; i < 4; ++i)
#pragma unroll
    for (int rg = 0; rg < 4; ++rg) {
      const int r = wm + i * 16 + quad * 4 + rg;
#pragma unroll
      for (int j = 0; j < 4; ++j)
        Pb[r * 136 + wn + j * 16 + r16] = f2bf_ru(acc[i][j][rg] * rmax[i][rg]);
    }
  __syncthreads();

  // ---- O = P V (swapped); on=32 waves only need j=0 (cols 32..47) ----
  const int om = (wave >> 1) * 64, on = (wave & 1) * 32;
  const int jn = (on == 0) ? 2 : 1;
  floatx4 oacc[4][2] = {};
  for (int kk = 0; kk < 4; ++kk) {
    const int k0 = kk * 32;
    short8 af[4], bfr[2];
#pragma unroll
    for (int i = 0; i < 4; ++i)
      af[i] = *(const short8*)&Pb[(om + i * 16 + r16) * 136 + k0 + quad * 8];
    for (int j = 0; j < jn; ++j) {
      const int row = on + j * 16 + r16;
      bfr[j] = *(const short8*)&vsT[row * 136 + ((row >> 3) & 3) * 8 + k0 + quad * 8];
    }
#pragma unroll
    for (int i = 0; i < 4; ++i)
      for (int j = 0; j < jn; ++j)
        oacc[i][j] = __builtin_amdgcn_mfma_f32_16x16x32_bf16(bfr[j], af[i], oacc[i][j], 0, 0, 0);
  }
#pragma unroll
  for (int i = 0; i < 4; ++i)
    for (int j = 0; j < jn; ++j) {
      const int d0 = on + j * 16 + quad * 4;
      const int sq = om + i * 16 + r16;
      s4v o4;
#pragma unroll
      for (int rg = 0; rg < 4; ++rg) o4[rg] = f2bf_ru(oacc[i][j][rg]);
      *(s4v*)(og + (long)sq * 48 + d0) = o4;
    }
}

// ---------------------------------------------------------------------------
// Pool over S + BN + GELU MLP head + uncertainty head.  Block per b.
// ---------------------------------------------------------------------------
__global__ __launch_bounds__(256)
void head_kernel(const short* __restrict__ hb, float* __restrict__ out,
                 const float* bn_w, const float* bn_b, const float* bn_mean, const float* bn_var,
                 const float* h1w, const float* h1b, const float* h2w, const float* h2b,
                 const float* h3w, const float* h3b,
                 const float* u1w, const float* u1b, const float* u2w, const float* u2b)
{
  __shared__ float psum[252][8];
  __shared__ float pooled[288], z[288], z1[144], z2[72], uu[72];
  const int b = blockIdx.x, tid = threadIdx.x;

  if (tid < 252) {
    const int cch = tid % 36, grp = tid / 36;
    float a[8];
#pragma unroll
    for (int j = 0; j < 8; ++j) a[j] = 0.f;
    for (int r = grp; r < 128; r += 7) {
      const short8 hv = *(const short8*)(hb + ((long)b * 128 + r) * 288 + cch * 8);
#pragma unroll
      for (int j = 0; j < 8; ++j) a[j] += bf2f(hv[j]);
    }
#pragma unroll
    for (int j = 0; j < 8; ++j) psum[tid][j] = a[j];
  }
  __syncthreads();
  for (int d = tid; d < 288; d += 256) {
    const int cch = d >> 3, j = d & 7;
    float s = 0.f;
#pragma unroll
    for (int g = 0; g < 7; ++g) s += psum[g * 36 + cch][j];
    pooled[d] = s * (1.f / 128.f);
  }
  __syncthreads();

  for (int d = tid; d < 288; d += 256) {
    const float p = pooled[d];
    z[d] = gelu_exact((p - bn_mean[d]) * rsqrtf(bn_var[d] + 1e-5f) * bn_w[d] + bn_b[d]);
  }
  __syncthreads();

  if (tid < 144) {
    float s = h1b[tid];
    for (int k = 0; k < 288; ++k) s += z[k] * h1w[tid * 288 + k];
    z1[tid] = gelu_exact(s);
  } else if (tid < 216) {
    const int t = tid - 144;
    float s = u1b[t];
    for (int k = 0; k < 288; ++k) s += pooled[k] * u1w[t * 288 + k];
    uu[t] = fmaxf(s, 0.f);
  }
  __syncthreads();

  if (tid < 72) {
    float s = h2b[tid];
    for (int k = 0; k < 144; ++k) s += z1[k] * h2w[tid * 144 + k];
    z2[tid] = gelu_exact(s);
  }
  __syncthreads();

  if (tid == 0) {
    float s = h3b[0];
    for (int k = 0; k < 72; ++k) s += z2[k] * h3w[k];
    out[b] = s;
  }
  if (tid == 64) {
    float s = u2b[0];
    for (int k = 0; k < 72; ++k) s += uu[k] * u2w[k];
    out[1024 + b] = (s > 20.f) ? s : log1pf(__expf(s));
  }
}

// ---------------------------------------------------------------------------
// Conversion / padding kernels
// ---------------------------------------------------------------------------
__global__ void conv_w_kernel(const float* __restrict__ src, short* __restrict__ dst,
                              int N, int K, int Npad, int Kpad, int total)
{
  const int i = blockIdx.x * 256 + threadIdx.x;
  if (i >= total) return;
  const int kk = i % Kpad;
  const int t  = i / Kpad;
  const int n  = t % Npad;
  const int l  = t / Npad;
  const float v = (n < N && kk < K) ? src[((long)l * N + n) * K + kk] : 0.f;
  dst[i] = f2bf(v);
}

__global__ void conv_b_kernel(const float* __restrict__ src, float* __restrict__ dst,
                              int N, int Npad, int total)
{
  const int i = blockIdx.x * 256 + threadIdx.x;
  if (i >= total) return;
  const int n = i % Npad, l = i / Npad;
  dst[i] = (n < N) ? src[l * N + n] : 0.f;
}

__global__ void conv_wqkv_kernel(const float* __restrict__ Wq, const float* __restrict__ Wk,
                                 const float* __restrict__ Wv, short* __restrict__ dst)
{
  const int i = blockIdx.x * 256 + threadIdx.x;
  if (i >= 4 * 1152 * 288) return;
  const int kk = i % 288;
  const int t  = i / 288;
  const int r  = t % 1152;
  const int l  = t / 1152;
  const int g  = r / 48, d = r - (r / 48) * 48;
  const int sec = g >> 3, head = g & 7;
  float v = 0.f;
  if (d < 41) {
    const float* W = (sec == 0) ? Wq : (sec == 1) ? Wk : Wv;
    v = W[((long)l * 328 + head * 41 + d) * 288 + kk];
  }
  dst[i] = f2bf(v);
}

__global__ void conv_bqkv_kernel(const float* __restrict__ bq, const float* __restrict__ bk,
                                 const float* __restrict__ bv, float* __restrict__ dst)
{
  const int i = blockIdx.x * 256 + threadIdx.x;
  if (i >= 4 * 1152) return;
  const int r = i % 1152, l = i / 1152;
  const int g = r / 48, d = r - (r / 48) * 48;
  const int sec = g >> 3, head = g & 7;
  float v = 0.f;
  if (d < 41) {
    const float* b = (sec == 0) ? bq : (sec == 1) ? bk : bv;
    v = b[l * 328 + head * 41 + d];
  }
  dst[i] = v;
}

__global__ void conv_wo_kernel(const float* __restrict__ Wo, short* __restrict__ dst)
{
  const int i = blockIdx.x * 256 + threadIdx.x;
  if (i >= 4 * 288 * 384) return;
  const int kk = i % 384;
  const int t  = i / 384;
  const int n  = t % 288;
  const int l  = t / 288;
  const int head = kk / 48, d = kk - head * 48;
  float v = 0.f;
  if (d < 41) v = Wo[((long)l * 288 + n) * 328 + head * 41 + d];
  dst[i] = f2bf(v);
}

__global__ void conv_x_kernel(const float* __restrict__ x, short* __restrict__ xb, int total)
{
  const int i = blockIdx.x * 256 + threadIdx.x;
  if (i >= total) return;
  const int c = i % 96;
  const int r = i / 96;
  xb[i] = f2bf((c < 83) ? x[(long)r * 83 + c] : 0.f);
}

__global__ void pe_kernel(const float* __restrict__ phase, float* __restrict__ pe_mod)
{
  const int i = blockIdx.x * 256 + threadIdx.x;
  if (i >= 128 * 384) return;
  const int d = i % 384, s = i / 384;
  float out = 0.f;
  if (d < 288) {
    const int pair = d >> 1;
    const float divv = expf((float)(2 * pair) * (-9.210340371976184f / 288.f));
    const float arg = (float)s * divv;
    const float v = (d & 1) ? cosf(arg) : sinf(arg);
    out = v * cosf(phase[d]);
  }
  pe_mod[i] = out;
}

// ---------------------------------------------------------------------------
extern "C" void kernel_launch(void* const* d_in, const int* in_sizes, int n_in,
                              void* d_out, int out_size, void* d_ws, size_t ws_size,
                              hipStream_t stream)
{
  (void)in_sizes; (void)n_in; (void)out_size;

  const float* x     = (const float*)d_in[0];
  const float* Wp    = (const float*)d_in[1];
  const float* bp    = (const float*)d_in[2];
  const float* phase = (const float*)d_in[3];
  const float* Wq    = (const float*)d_in[4];
  const float* bq    = (const float*)d_in[5];
  const float* Wk    = (const float*)d_in[6];
  const float* bk    = (const float*)d_in[7];
  const float* Wv    = (const float*)d_in[8];
  const float* bv    = (const float*)d_in[9];
  const float* Wo    = (const float*)d_in[10];
  const float* bo    = (const float*)d_in[11];
  const float* temp  = (const float*)d_in[12];
  const float* qscale= (const float*)d_in[13];
  const float* Wf1   = (const float*)d_in[14];
  const float* bf1   = (const float*)d_in[15];
  const float* Wf2   = (const float*)d_in[16];
  const float* bf2   = (const float*)d_in[17];
  const float* n1w   = (const float*)d_in[18];
  const float* n1b   = (const float*)d_in[19];
  const float* n2w   = (const float*)d_in[20];
  const float* n2b   = (const float*)d_in[21];
  const float* skip  = (const float*)d_in[22];
  const float* bn_w  = (const float*)d_in[23];
  const float* bn_b  = (const float*)d_in[24];
  const float* bn_mean=(const float*)d_in[25];
  const float* bn_var= (const float*)d_in[26];
  const float* h1w   = (const float*)d_in[27];
  const float* h1b   = (const float*)d_in[28];
  const float* h2w   = (const float*)d_in[29];
  const float* h2b   = (const float*)d_in[30];
  const float* h3w   = (const float*)d_in[31];
  const float* h3b   = (const float*)d_in[32];
  const float* u1w   = (const float*)d_in[33];
  const float* u1b   = (const float*)d_in[34];
  const float* u2w   = (const float*)d_in[35];
  const float* u2b   = (const float*)d_in[36];

  char* ws = (char*)d_ws;
  size_t off = 0;
  auto alloc = [&](size_t n) -> char* {
    off = (off + 255) & ~(size_t)255;
    char* p = ws + off;
    off += n;
    return p;
  };

  const long M = 131072;

  short* h_bf   = (short*)alloc((size_t)M * 288 * 2);
  float* pe_mod = (float*)alloc(128 * 384 * 4);

  short* Wp_b   = (short*)alloc((size_t)384 * 96 * 2);
  short* Wqkv_b = (short*)alloc((size_t)4 * 1152 * 288 * 2);
  short* Wo_b   = (short*)alloc((size_t)4 * 288 * 384 * 2);
  short* Wf1_b  = (short*)alloc((size_t)4 * 1408 * 288 * 2);
  short* Wf2_b  = (short*)alloc((size_t)4 * 384 * 1344 * 2);

  float* bp_p   = (float*)alloc((size_t)384 * 4);
  float* bqkv_p = (float*)alloc((size_t)4 * 1152 * 4);
  float* bo_p   = (float*)alloc((size_t)4 * 384 * 4);
  float* bf1_p  = (float*)alloc((size_t)4 * 1408 * 4);
  float* bf2_p  = (float*)alloc((size_t)4 * 384 * 4);

  const size_t fixed = off;
  int NC = 1;
  while (NC < 16 && fixed + (size_t)(M / NC) * 2304 + (1u << 20) > ws_size) NC <<= 1;
  const long Mc = M / NC;
  const long Mc2 = Mc / 2;
  const long sec = Mc * 48;

  char* R = alloc((size_t)Mc * 2304);
  short* qkv_bf = (short*)R;                              // [24][Mc][48] head-major
  short* f_bf   = (short*)R;                              // [Mc2][1344] (subchunk)
  short* x_bfc  = (short*)R;                              // [Mc][96]

  const dim3 blk(256);

  auto conv_w = [&](const float* s, short* d, int N, int K, int Np, int Kp, int L) {
    const int total = L * Np * Kp;
    conv_w_kernel<<<dim3((total + 255) / 256), blk, 0, stream>>>(s, d, N, K, Np, Kp, total);
  };
  auto conv_b = [&](const float* s, float* d, int N, int Np, int L) {
    const int total = L * Np;
    conv_b_kernel<<<dim3((total + 255) / 256), blk, 0, stream>>>(s, d, N, Np, total);
  };
  conv_w(Wp,  Wp_b,  288,   83, 384,   96, 1);
  conv_wqkv_kernel<<<dim3((4 * 1152 * 288 + 255) / 256), blk, 0, stream>>>(Wq, Wk, Wv, Wqkv_b);
  conv_wo_kernel<<<dim3((4 * 288 * 384 + 255) / 256), blk, 0, stream>>>(Wo, Wo_b);
  conv_w(Wf1, Wf1_b, 1315, 288, 1408, 288, 4);
  conv_w(Wf2, Wf2_b, 288, 1315, 384, 1344, 4);
  conv_b(bp,  bp_p,  288,  384, 1);
  conv_bqkv_kernel<<<dim3((4 * 1152 + 255) / 256), blk, 0, stream>>>(bq, bk, bv, bqkv_p);
  conv_b(bo,  bo_p,  288,  384, 4);
  conv_b(bf1, bf1_p, 1315, 1408, 4);
  conv_b(bf2, bf2_p, 288,  384, 4);
  pe_kernel<<<dim3((128 * 384 + 255) / 256), blk, 0, stream>>>(phase, pe_mod);

  auto gemm = [&](int mode, const short* A, const short* Bmat, const float* bias,
                  short* C, const float* pe, int K, int lda, int ldb, int ldc,
                  int Nstore, int NT, long Mrows, long hstride) {
    const dim3 grid((unsigned)((Mrows / 128) * NT));
    switch (mode) {
      case 0: gemm_kernel<0><<<grid, blk, 0, stream>>>(A, Bmat, bias, C, pe, K, lda, ldb, ldc, Nstore, NT, hstride); break;
      case 1: gemm_kernel<1><<<grid, blk, 0, stream>>>(A, Bmat, bias, C, pe, K, lda, ldb, ldc, Nstore, NT, hstride); break;
      case 2: gemm_kernel<2><<<grid, blk, 0, stream>>>(A, Bmat, bias, C, pe, K, lda, ldb, ldc, Nstore, NT, hstride); break;
      default: gemm_kernel<3><<<grid, blk, 0, stream>>>(A, Bmat, bias, C, pe, K, lda, ldb, ldc, Nstore, NT, hstride); break;
    }
  };

  for (int c = 0; c < NC; ++c) {
    const float* x_c = x + (size_t)c * Mc * 83;
    short* h_c = h_bf + (size_t)c * Mc * 288;

    const int xtot = (int)(Mc * 96);
    conv_x_kernel<<<dim3((xtot + 255) / 256), blk, 0, stream>>>(x_c, x_bfc, xtot);

    gemm(2, x_bfc, Wp_b, bp_p, h_c, pe_mod, 96, 96, 96, 288, 288, 3, Mc, 0);

    for (int l = 0; l < 4; ++l) {
      const short* Wqkv_l = Wqkv_b + (size_t)l * 1152 * 288;
      const short* Wo_l   = Wo_b   + (size_t)l * 288 * 384;
      const short* Wf1_l  = Wf1_b  + (size_t)l * 1408 * 288;
      const short* Wf2_l  = Wf2_b  + (size_t)l * 384 * 1344;

      // fused QKV -> head-major [24][Mc][48]
      gemm(3, h_c, Wqkv_l, bqkv_p + l * 1152, qkv_bf, nullptr,
           288, 288, 288, 0, 1152, 9, Mc, sec);

      attn_kernel<<<dim3((unsigned)(Mc / 128), 8), blk, 0, stream>>>(
          qkv_bf, temp, qscale, l, Mc);

      // Wo + residual + LN1: A = o (head-major v-section), K=384
      gemm_ln_kernel<true><<<dim3((unsigned)(Mc / 128)), dim3(512), 0, stream>>>(
          qkv_bf + 16 * sec, Wo_l, bo_p + l * 384, h_c, n1w + l * 288, n1b + l * 288,
          skip, l, 1, 384, 48, 384, sec);

      // FFN over 2 sub-chunks (f reuses the qkv region)
      for (int s = 0; s < 2; ++s) {
        short* h_s = h_c + (size_t)s * Mc2 * 288;
        gemm(1, h_s, Wf1_l, bf1_p + l * 1408, f_bf, nullptr,
             288, 288, 288, 1344, 1344, 11, Mc2, 0);
        gemm_ln_kernel<false><<<dim3((unsigned)(Mc2 / 128)), dim3(512), 0, stream>>>(
            f_bf, Wf2_l, bf2_p + l * 384, h_s, n2w + l * 288, n2b + l * 288,
            skip, l, 0, 1344, 1344, 1344, 0);
      }
    }
  }

  head_kernel<<<dim3(1024), blk, 0, stream>>>(h_bf, (float*)d_out,
      bn_w, bn_b, bn_mean, bn_var,
      h1w, h1b, h2w, h2b, h3w, h3b,
      u1w, u1b, u2w, u2b);
}

// Round 10
// 3702.349 us; speedup vs baseline: 1.0737x; 1.0737x over previous
//
#include <hip/hip_runtime.h>
#include <cstdint>

typedef __attribute__((ext_vector_type(8))) short short8;
typedef __attribute__((ext_vector_type(4))) short s4v;
typedef __attribute__((ext_vector_type(4))) float floatx4;

#define DEV __device__ __forceinline__

DEV short f2bf(float f) {
  unsigned u = __builtin_bit_cast(unsigned, f);
  u += 0x7fffu + ((u >> 16) & 1u);
  return (short)(u >> 16);
}
DEV short f2bf_ru(float f) {
  unsigned u = __builtin_bit_cast(unsigned, f);
  return (short)((u + 0x8000u) >> 16);
}
DEV float bf2f(short s) {
  unsigned u = ((unsigned)(unsigned short)s) << 16;
  return __builtin_bit_cast(float, u);
}
DEV float gelu_exact(float x) {
  return 0.5f * x * (1.0f + erff(x * 0.70710678118654752f));
}
DEV float gelu_fast(float x) {
  const float t2 = 1.5957691216057308f * (x + 0.044715f * x * x * x);
  return x / (1.0f + __expf(-t2));
}
DEV void gload16(const void* g, void* l) {
  __builtin_amdgcn_global_load_lds((const __attribute__((address_space(1))) void*)g,
                                   (__attribute__((address_space(3))) void*)l,
                                   16, 0, 0);
}

// ---------------------------------------------------------------------------
// 128x128-tile bf16 MFMA GEMM, swapped-operand epilogue.
// MODE 0: C = v + bias ; MODE 1: gelu ; MODE 2: + pe ; MODE 3: head-major store
// ---------------------------------------------------------------------------
template<int MODE>
__global__ __launch_bounds__(256)
void gemm_kernel(const short* __restrict__ A, const short* __restrict__ Bw,
                 const float* __restrict__ bias, short* __restrict__ C,
                 const float* __restrict__ pe,
                 int K, int lda, int ldb, int ldc, int Nstore, int NT, long hstride)
{
  __shared__ __align__(16) short lds[128 * 136];
  short* As = lds;
  short* Bs = lds + 128 * 32;
  short* Ct = lds;

  const int tid  = threadIdx.x;
  const int wave = tid >> 6, lane = tid & 63;
  const int quad = lane >> 4, r16 = lane & 15;
  const int per = gridDim.x >> 3;
  const int gti = (blockIdx.x & 7) * per + (blockIdx.x >> 3);
  const int mt = gti / NT, nt = gti - mt * NT;
  const int wm = (wave >> 1) * 64, wn = (wave & 1) * 64;

  const long Abase = (long)mt * 128 * lda;
  const long Bbase = (long)nt * 128 * ldb;

  const int row0 = tid >> 2,         cc0 = (tid & 3) ^ ((row0 >> 1) & 3);
  const int row1 = (256 + tid) >> 2, cc1 = ((256 + tid) & 3) ^ ((row1 >> 1) & 3);

  floatx4 acc[4][4] = {};

  for (int k0 = 0; k0 < K; k0 += 32) {
    __syncthreads();
    gload16(A  + Abase + (long)row0 * lda + k0 + cc0 * 8, &As[(0 * 256 + wave * 64) * 8]);
    gload16(A  + Abase + (long)row1 * lda + k0 + cc1 * 8, &As[(1 * 256 + wave * 64) * 8]);
    gload16(Bw + Bbase + (long)row0 * ldb + k0 + cc0 * 8, &Bs[(0 * 256 + wave * 64) * 8]);
    gload16(Bw + Bbase + (long)row1 * ldb + k0 + cc1 * 8, &Bs[(1 * 256 + wave * 64) * 8]);
    __syncthreads();

    short8 af[4], bfr[4];
#pragma unroll
    for (int i = 0; i < 4; ++i) {
      const int R = wm + i * 16 + r16;
      af[i] = *(const short8*)&As[R * 32 + (quad ^ ((R >> 1) & 3)) * 8];
    }
#pragma unroll
    for (int j = 0; j < 4; ++j) {
      const int R = wn + j * 16 + r16;
      bfr[j] = *(const short8*)&Bs[R * 32 + (quad ^ ((R >> 1) & 3)) * 8];
    }
#pragma unroll
    for (int i = 0; i < 4; ++i)
#pragma unroll
      for (int j = 0; j < 4; ++j)
        acc[i][j] = __builtin_amdgcn_mfma_f32_16x16x32_bf16(bfr[j], af[i], acc[i][j], 0, 0, 0);
  }

  const int mb0 = mt * 128, tb = nt * 128;

  __syncthreads();
#pragma unroll
  for (int j = 0; j < 4; ++j) {
    const int n0 = wn + j * 16 + quad * 4;
    const floatx4 b4 = *(const floatx4*)&bias[tb + n0];
#pragma unroll
    for (int i = 0; i < 4; ++i) {
      const int m = wm + i * 16 + r16;
      floatx4 v = acc[i][j] + b4;
      if (MODE == 1) {
#pragma unroll
        for (int rg = 0; rg < 4; ++rg) v[rg] = gelu_fast(v[rg]);
      }
      if (MODE == 2) {
        const floatx4 p4 = *(const floatx4*)&pe[((mb0 + m) & 127) * 384 + tb + n0];
        v = v + p4;
      }
      s4v o4;
#pragma unroll
      for (int rg = 0; rg < 4; ++rg) o4[rg] = f2bf_ru(v[rg]);
      *(s4v*)&Ct[m * 136 + n0] = o4;
    }
  }
  __syncthreads();

#pragma unroll
  for (int rr = 0; rr < 8; ++rr) {
    const int chunk = rr * 256 + tid;
    const int row = chunk >> 4, ch = chunk & 15;
    const int gcol = tb + ch * 8;
    if (MODE == 3) {
      const int g = gcol / 48, d0 = gcol - g * 48;
      *(short8*)(C + (long)g * hstride + (long)(mb0 + row) * 48 + d0) =
          *(const short8*)&Ct[row * 136 + ch * 8];
    } else if (gcol < Nstore) {
      *(short8*)(C + (long)(mb0 + row) * ldc + gcol) = *(const short8*)&Ct[row * 136 + ch * 8];
    }
  }
}

// ---------------------------------------------------------------------------
// Fused GEMM + residual + LayerNorm, N=288 exact.  M-tile 128, 512 threads.
// ---------------------------------------------------------------------------
template<bool AHEAD>
__global__ __launch_bounds__(512, 4)
void gemm_ln_kernel(const short* __restrict__ A, const short* __restrict__ Bw,
                    const float* __restrict__ bias, short* __restrict__ h,
                    const float* __restrict__ lnw, const float* __restrict__ lnb,
                    const float* __restrict__ skip_p, int layer, int use_skip,
                    int K, int lda, int ldb, long ahs)
{
  __shared__ __align__(16) short lds[128 * 296];
  short* As = lds;                 // [128][32]
  short* Bs = lds + 128 * 32;      // [288][32]
  short* Hs = lds;                 // [128][296]

  const int tid  = threadIdx.x;
  const int wave = tid >> 6, lane = tid & 63;
  const int quad = lane >> 4, r16 = lane & 15;
  const int mt = blockIdx.x;
  const long mrow0 = (long)mt * 128;

  floatx4 acc[18] = {};

  for (int k0 = 0; k0 < K; k0 += 32) {
    __syncthreads();
    for (int c = tid; c < 1664; c += 512) {
      const void* src;
      if (c < 512) {
        const int row = c >> 2, cc = (c & 3) ^ ((row >> 1) & 3);
        if (AHEAD) {
          const int kc = k0 + cc * 8;
          const int g = kc / 48, d = kc - g * 48;
          src = A + (long)g * ahs + (mrow0 + row) * 48 + d;
        } else {
          src = A + (mrow0 + row) * lda + k0 + cc * 8;
        }
      } else {
        const int cb = c - 512;
        const int row = cb >> 2, cc = (cb & 3) ^ ((row >> 1) & 3);
        src = Bw + (long)row * ldb + k0 + cc * 8;
      }
      gload16(src, &lds[(size_t)(c & ~63) * 8]);
    }
    __syncthreads();

    const int Ra = wave * 16 + r16;
    const short8 af = *(const short8*)&As[Ra * 32 + (quad ^ ((Ra >> 1) & 3)) * 8];
#pragma unroll
    for (int t = 0; t < 18; ++t) {
      const int Rb = t * 16 + r16;
      const short8 bfr = *(const short8*)&Bs[Rb * 32 + (quad ^ ((Rb >> 1) & 3)) * 8];
      acc[t] = __builtin_amdgcn_mfma_f32_16x16x32_bf16(bfr, af, acc[t], 0, 0, 0);
    }
  }

  __syncthreads();
  for (int c = tid; c < 4608; c += 512) {
    const int row = c / 36, ch = c - row * 36;
    *(short8*)&Hs[row * 296 + ch * 8] =
        *(const short8*)(h + (mrow0 + row) * 288 + ch * 8);
  }
  __syncthreads();

  const float skipv = use_skip ? skip_p[layer] : 1.0f;
  const int m = wave * 16 + r16;

  float ps = 0.f, pss = 0.f;
#pragma unroll
  for (int t = 0; t < 18; ++t) {
    const int n0 = t * 16 + quad * 4;
    const floatx4 b4 = *(const floatx4*)&bias[n0];
    const s4v h4 = *(const s4v*)&Hs[m * 296 + n0];
#pragma unroll
    for (int rg = 0; rg < 4; ++rg) {
      const float y = bf2f(h4[rg]) + skipv * (acc[t][rg] + b4[rg]);
      acc[t][rg] = y;
      ps += y; pss += y * y;
    }
  }
  ps  += __shfl_xor(ps, 16);  ps  += __shfl_xor(ps, 32);
  pss += __shfl_xor(pss, 16); pss += __shfl_xor(pss, 32);
  const float mean = ps * (1.f / 288.f);
  const float var  = pss * (1.f / 288.f) - mean * mean;
  const float rstd = rsqrtf(var + 1e-5f);

#pragma unroll
  for (int t = 0; t < 18; ++t) {
    const int n0 = t * 16 + quad * 4;
    const floatx4 w4 = *(const floatx4*)&lnw[n0];
    const floatx4 l4 = *(const floatx4*)&lnb[n0];
    s4v o4;
#pragma unroll
    for (int rg = 0; rg < 4; ++rg)
      o4[rg] = f2bf_ru((acc[t][rg] - mean) * rstd * w4[rg] + l4[rg]);
    *(s4v*)&Hs[m * 296 + n0] = o4;
  }
  __syncthreads();

  for (int c = tid; c < 4608; c += 512) {
    const int row = c / 36, ch = c - row * 36;
    *(short8*)(h + (mrow0 + row) * 288 + ch * 8) =
        *(const short8*)&Hs[row * 296 + ch * 8];
  }
}

// ---------------------------------------------------------------------------
// Attention.  qkv head-major [24][Mc][48]; q pre-scaled by 1/(sqrt(41)*temp)
// at weight conversion.  QK^T uses swapped operands so the P write is packed
// b64 (lane holds 4 consecutive sk).  o overwrites the v-section.
// ---------------------------------------------------------------------------
__global__ __launch_bounds__(256)
void attn_kernel(short* __restrict__ qkv,
                 const float* __restrict__ qscale, int layer, long Mc)
{
  __shared__ __align__(16) short qk[2 * 128 * 72];   // qs|ks, later Pb[128][136]
  __shared__ __align__(16) short vsT[48 * 136 + 32]; // [d][s], skew ((d>>3)&3)*8
  __shared__ float red[2][2][64];

  short* qs = qk;
  short* ks = qk + 128 * 72;
  short* Pb = qk;

  const int b = blockIdx.x, h = blockIdx.y;
  const int tid = threadIdx.x;
  const long sec = Mc * 48;
  const short* qg = qkv + (long)h * sec + (long)b * 128 * 48;
  const short* kg = qg + 8 * sec;
  const short* vg = qg + 16 * sec;
  short* og = qkv + (long)(16 + h) * sec + (long)b * 128 * 48;

  // coalesced q,k loads (96 B rows)
  for (int c = tid; c < 768; c += 256) {
    const int s = c / 6, dc = c - (c / 6) * 6;
    *(short8*)&qs[s * 72 + dc * 8] = *(const short8*)(qg + (long)s * 48 + dc * 8);
    *(short8*)&ks[s * 72 + dc * 8] = *(const short8*)(kg + (long)s * 48 + dc * 8);
  }
  {
    short8 z;
#pragma unroll
    for (int j = 0; j < 8; ++j) z[j] = 0;
    for (int c = tid; c < 384; c += 256) {
      const int s = c / 3, t = c - (c / 3) * 3;
      *(short8*)&qs[s * 72 + 48 + t * 8] = z;
      *(short8*)&ks[s * 72 + 48 + t * 8] = z;
    }
  }
  // v transpose: per-instruction lanes = one d-row x 64 consecutive s
  for (int c = tid; c < 768; c += 256) {
    const int s = c & 127, dc = c >> 7;
    const short8 tv = *(const short8*)(vg + (long)s * 48 + dc * 8);
#pragma unroll
    for (int j = 0; j < 8; ++j) {
      const int row = dc * 8 + j;
      vsT[row * 136 + ((row >> 3) & 3) * 8 + s] = tv[j];
    }
  }
  __syncthreads();

  const int wave = tid >> 6, lane = tid & 63;
  const int quad = lane >> 4, r16 = lane & 15;
  const int wm = (wave >> 1) * 64, wn = (wave & 1) * 64;
  const int rh = wave >> 1, ch = wave & 1;
  const float qsc = qscale[layer * 8 + h];

  // ---- scores: SWAPPED operands -> acc[i][j]: sq=wm+i*16+r16,
  //      sk=wn+j*16+quad*4+rg (invs folded into q at conversion) ----
  floatx4 acc[4][4] = {};
#pragma unroll
  for (int kk = 0; kk < 2; ++kk) {
    const int k0 = kk * 32;
    short8 af[4], bfr[4];
#pragma unroll
    for (int i = 0; i < 4; ++i)
      af[i] = *(const short8*)&qs[(wm + i * 16 + r16) * 72 + k0 + quad * 8];
#pragma unroll
    for (int j = 0; j < 4; ++j)
      bfr[j] = *(const short8*)&ks[(wn + j * 16 + r16) * 72 + k0 + quad * 8];
#pragma unroll
    for (int i = 0; i < 4; ++i)
#pragma unroll
      for (int j = 0; j < 4; ++j)
        acc[i][j] = __builtin_amdgcn_mfma_f32_16x16x32_bf16(bfr[j], af[i], acc[i][j], 0, 0, 0);
  }

  // ---- softmax over sk for fixed sq=(i,r16): in-reg 16 + shfl 16,32 ----
  float rmax[4], rsum[4];
#pragma unroll
  for (int i = 0; i < 4; ++i) {
    float m = acc[i][0][0];
#pragma unroll
    for (int j = 0; j < 4; ++j)
#pragma unroll
      for (int rg = 0; rg < 4; ++rg) m = fmaxf(m, acc[i][j][rg]);
    m = fmaxf(m, __shfl_xor(m, 16));
    m = fmaxf(m, __shfl_xor(m, 32));
    rmax[i] = m;
  }
  if (lane < 16)
#pragma unroll
    for (int i = 0; i < 4; ++i) red[rh][ch][i * 16 + r16] = rmax[i];
  __syncthreads();
#pragma unroll
  for (int i = 0; i < 4; ++i)
    rmax[i] = fmaxf(red[rh][0][i * 16 + r16], red[rh][1][i * 16 + r16]);

#pragma unroll
  for (int i = 0; i < 4; ++i) {
    float s = 0.f;
#pragma unroll
    for (int j = 0; j < 4; ++j)
#pragma unroll
      for (int rg = 0; rg < 4; ++rg) {
        const float e = __expf(acc[i][j][rg] - rmax[i]);
        acc[i][j][rg] = e;
        s += e;
      }
    s += __shfl_xor(s, 16);
    s += __shfl_xor(s, 32);
    rsum[i] = s;
  }
  __syncthreads();
  if (lane < 16)
#pragma unroll
    for (int i = 0; i < 4; ++i) red[rh][ch][i * 16 + r16] = rsum[i];
  __syncthreads();
#pragma unroll
  for (int i = 0; i < 4; ++i)
    rmax[i] = qsc / (red[rh][0][i * 16 + r16] + red[rh][1][i * 16 + r16]);

  // ---- packed P write: b64 per (i,j) ----
#pragma unroll
  for (int i = 0; i < 4; ++i) {
    const int sq = wm + i * 16 + r16;
#pragma unroll
    for (int j = 0; j < 4; ++j) {
      const int sk0 = wn + j * 16 + quad * 4;
      s4v p4;
#pragma unroll
      for (int rg = 0; rg < 4; ++rg) p4[rg] = f2bf_ru(acc[i][j][rg] * rmax[i]);
      *(s4v*)&Pb[sq * 136 + sk0] = p4;
    }
  }
  __syncthreads();

  // ---- O = P V (swapped); on=32 waves only need j=0 ----
  const int om = (wave >> 1) * 64, on = (wave & 1) * 32;
  const int jn = (on == 0) ? 2 : 1;
  floatx4 oacc[4][2] = {};
  for (int kk = 0; kk < 4; ++kk) {
    const int k0 = kk * 32;
    short8 af[4], bfr[2];
#pragma unroll
    for (int i = 0; i < 4; ++i)
      af[i] = *(const short8*)&Pb[(om + i * 16 + r16) * 136 + k0 + quad * 8];
    for (int j = 0; j < jn; ++j) {
      const int row = on + j * 16 + r16;
      bfr[j] = *(const short8*)&vsT[row * 136 + ((row >> 3) & 3) * 8 + k0 + quad * 8];
    }
#pragma unroll
    for (int i = 0; i < 4; ++i)
      for (int j = 0; j < jn; ++j)
        oacc[i][j] = __builtin_amdgcn_mfma_f32_16x16x32_bf16(bfr[j], af[i], oacc[i][j], 0, 0, 0);
  }
#pragma unroll
  for (int i = 0; i < 4; ++i)
    for (int j = 0; j < jn; ++j) {
      const int d0 = on + j * 16 + quad * 4;
      const int sq = om + i * 16 + r16;
      s4v o4;
#pragma unroll
      for (int rg = 0; rg < 4; ++rg) o4[rg] = f2bf_ru(oacc[i][j][rg]);
      *(s4v*)(og + (long)sq * 48 + d0) = o4;
    }
}

// ---------------------------------------------------------------------------
// Pool over S + BN + GELU MLP head + uncertainty head.  Block per b.
// ---------------------------------------------------------------------------
__global__ __launch_bounds__(256)
void head_kernel(const short* __restrict__ hb, float* __restrict__ out,
                 const float* bn_w, const float* bn_b, const float* bn_mean, const float* bn_var,
                 const float* h1w, const float* h1b, const float* h2w, const float* h2b,
                 const float* h3w, const float* h3b,
                 const float* u1w, const float* u1b, const float* u2w, const float* u2b)
{
  __shared__ float psum[252][8];
  __shared__ float pooled[288], z[288], z1[144], z2[72], uu[72];
  const int b = blockIdx.x, tid = threadIdx.x;

  if (tid < 252) {
    const int cch = tid % 36, grp = tid / 36;
    float a[8];
#pragma unroll
    for (int j = 0; j < 8; ++j) a[j] = 0.f;
    for (int r = grp; r < 128; r += 7) {
      const short8 hv = *(const short8*)(hb + ((long)b * 128 + r) * 288 + cch * 8);
#pragma unroll
      for (int j = 0; j < 8; ++j) a[j] += bf2f(hv[j]);
    }
#pragma unroll
    for (int j = 0; j < 8; ++j) psum[tid][j] = a[j];
  }
  __syncthreads();
  for (int d = tid; d < 288; d += 256) {
    const int cch = d >> 3, j = d & 7;
    float s = 0.f;
#pragma unroll
    for (int g = 0; g < 7; ++g) s += psum[g * 36 + cch][j];
    pooled[d] = s * (1.f / 128.f);
  }
  __syncthreads();

  for (int d = tid; d < 288; d += 256) {
    const float p = pooled[d];
    z[d] = gelu_exact((p - bn_mean[d]) * rsqrtf(bn_var[d] + 1e-5f) * bn_w[d] + bn_b[d]);
  }
  __syncthreads();

  if (tid < 144) {
    float s = h1b[tid];
    for (int k = 0; k < 288; ++k) s += z[k] * h1w[tid * 288 + k];
    z1[tid] = gelu_exact(s);
  } else if (tid < 216) {
    const int t = tid - 144;
    float s = u1b[t];
    for (int k = 0; k < 288; ++k) s += pooled[k] * u1w[t * 288 + k];
    uu[t] = fmaxf(s, 0.f);
  }
  __syncthreads();

  if (tid < 72) {
    float s = h2b[tid];
    for (int k = 0; k < 144; ++k) s += z1[k] * h2w[tid * 144 + k];
    z2[tid] = gelu_exact(s);
  }
  __syncthreads();

  if (tid == 0) {
    float s = h3b[0];
    for (int k = 0; k < 72; ++k) s += z2[k] * h3w[k];
    out[b] = s;
  }
  if (tid == 64) {
    float s = u2b[0];
    for (int k = 0; k < 72; ++k) s += uu[k] * u2w[k];
    out[1024 + b] = (s > 20.f) ? s : log1pf(__expf(s));
  }
}

// ---------------------------------------------------------------------------
// Conversion / padding kernels
// ---------------------------------------------------------------------------
__global__ void conv_w_kernel(const float* __restrict__ src, short* __restrict__ dst,
                              int N, int K, int Npad, int Kpad, int total)
{
  const int i = blockIdx.x * 256 + threadIdx.x;
  if (i >= total) return;
  const int kk = i % Kpad;
  const int t  = i / Kpad;
  const int n  = t % Npad;
  const int l  = t / Npad;
  const float v = (n < N && kk < K) ? src[((long)l * N + n) * K + kk] : 0.f;
  dst[i] = f2bf(v);
}

__global__ void conv_b_kernel(const float* __restrict__ src, float* __restrict__ dst,
                              int N, int Npad, int total)
{
  const int i = blockIdx.x * 256 + threadIdx.x;
  if (i >= total) return;
  const int n = i % Npad, l = i / Npad;
  dst[i] = (n < N) ? src[l * N + n] : 0.f;
}

// q-section (sec==0) pre-scaled by 1/(sqrt(41)*temp[l])
__global__ void conv_wqkv_kernel(const float* __restrict__ Wq, const float* __restrict__ Wk,
                                 const float* __restrict__ Wv, const float* __restrict__ temp,
                                 short* __restrict__ dst)
{
  const int i = blockIdx.x * 256 + threadIdx.x;
  if (i >= 4 * 1152 * 288) return;
  const int kk = i % 288;
  const int t  = i / 288;
  const int r  = t % 1152;
  const int l  = t / 1152;
  const int g  = r / 48, d = r - (r / 48) * 48;
  const int sec = g >> 3, head = g & 7;
  float v = 0.f;
  if (d < 41) {
    const float* W = (sec == 0) ? Wq : (sec == 1) ? Wk : Wv;
    v = W[((long)l * 328 + head * 41 + d) * 288 + kk];
    if (sec == 0) v *= 1.0f / (6.4031242374328485f * temp[l]);
  }
  dst[i] = f2bf(v);
}

__global__ void conv_bqkv_kernel(const float* __restrict__ bq, const float* __restrict__ bk,
                                 const float* __restrict__ bv, const float* __restrict__ temp,
                                 float* __restrict__ dst)
{
  const int i = blockIdx.x * 256 + threadIdx.x;
  if (i >= 4 * 1152) return;
  const int r = i % 1152, l = i / 1152;
  const int g = r / 48, d = r - (r / 48) * 48;
  const int sec = g >> 3, head = g & 7;
  float v = 0.f;
  if (d < 41) {
    const float* b = (sec == 0) ? bq : (sec == 1) ? bk : bv;
    v = b[l * 328 + head * 41 + d];
    if (sec == 0) v *= 1.0f / (6.4031242374328485f * temp[l]);
  }
  dst[i] = v;
}

__global__ void conv_wo_kernel(const float* __restrict__ Wo, short* __restrict__ dst)
{
  const int i = blockIdx.x * 256 + threadIdx.x;
  if (i >= 4 * 288 * 384) return;
  const int kk = i % 384;
  const int t  = i / 384;
  const int n  = t % 288;
  const int l  = t / 288;
  const int head = kk / 48, d = kk - head * 48;
  float v = 0.f;
  if (d < 41) v = Wo[((long)l * 288 + n) * 328 + head * 41 + d];
  dst[i] = f2bf(v);
}

__global__ void conv_x_kernel(const float* __restrict__ x, short* __restrict__ xb, int total)
{
  const int i = blockIdx.x * 256 + threadIdx.x;
  if (i >= total) return;
  const int c = i % 96;
  const int r = i / 96;
  xb[i] = f2bf((c < 83) ? x[(long)r * 83 + c] : 0.f);
}

__global__ void pe_kernel(const float* __restrict__ phase, float* __restrict__ pe_mod)
{
  const int i = blockIdx.x * 256 + threadIdx.x;
  if (i >= 128 * 384) return;
  const int d = i % 384, s = i / 384;
  float out = 0.f;
  if (d < 288) {
    const int pair = d >> 1;
    const float divv = expf((float)(2 * pair) * (-9.210340371976184f / 288.f));
    const float arg = (float)s * divv;
    const float v = (d & 1) ? cosf(arg) : sinf(arg);
    out = v * cosf(phase[d]);
  }
  pe_mod[i] = out;
}

// ---------------------------------------------------------------------------
extern "C" void kernel_launch(void* const* d_in, const int* in_sizes, int n_in,
                              void* d_out, int out_size, void* d_ws, size_t ws_size,
                              hipStream_t stream)
{
  (void)in_sizes; (void)n_in; (void)out_size;

  const float* x     = (const float*)d_in[0];
  const float* Wp    = (const float*)d_in[1];
  const float* bp    = (const float*)d_in[2];
  const float* phase = (const float*)d_in[3];
  const float* Wq    = (const float*)d_in[4];
  const float* bq    = (const float*)d_in[5];
  const float* Wk    = (const float*)d_in[6];
  const float* bk    = (const float*)d_in[7];
  const float* Wv    = (const float*)d_in[8];
  const float* bv    = (const float*)d_in[9];
  const float* Wo    = (const float*)d_in[10];
  const float* bo    = (const float*)d_in[11];
  const float* temp  = (const float*)d_in[12];
  const float* qscale= (const float*)d_in[13];
  const float* Wf1   = (const float*)d_in[14];
  const float* bf1   = (const float*)d_in[15];
  const float* Wf2   = (const float*)d_in[16];
  const float* bf2   = (const float*)d_in[17];
  const float* n1w   = (const float*)d_in[18];
  const float* n1b   = (const float*)d_in[19];
  const float* n2w   = (const float*)d_in[20];
  const float* n2b   = (const float*)d_in[21];
  const float* skip  = (const float*)d_in[22];
  const float* bn_w  = (const float*)d_in[23];
  const float* bn_b  = (const float*)d_in[24];
  const float* bn_mean=(const float*)d_in[25];
  const float* bn_var= (const float*)d_in[26];
  const float* h1w   = (const float*)d_in[27];
  const float* h1b   = (const float*)d_in[28];
  const float* h2w   = (const float*)d_in[29];
  const float* h2b   = (const float*)d_in[30];
  const float* h3w   = (const float*)d_in[31];
  const float* h3b   = (const float*)d_in[32];
  const float* u1w   = (const float*)d_in[33];
  const float* u1b   = (const float*)d_in[34];
  const float* u2w   = (const float*)d_in[35];
  const float* u2b   = (const float*)d_in[36];

  char* ws = (char*)d_ws;
  size_t off = 0;
  auto alloc = [&](size_t n) -> char* {
    off = (off + 255) & ~(size_t)255;
    char* p = ws + off;
    off += n;
    return p;
  };

  const long M = 131072;

  short* h_bf   = (short*)alloc((size_t)M * 288 * 2);
  float* pe_mod = (float*)alloc(128 * 384 * 4);

  short* Wp_b   = (short*)alloc((size_t)384 * 96 * 2);
  short* Wqkv_b = (short*)alloc((size_t)4 * 1152 * 288 * 2);
  short* Wo_b   = (short*)alloc((size_t)4 * 288 * 384 * 2);
  short* Wf1_b  = (short*)alloc((size_t)4 * 1408 * 288 * 2);
  short* Wf2_b  = (short*)alloc((size_t)4 * 384 * 1344 * 2);

  float* bp_p   = (float*)alloc((size_t)384 * 4);
  float* bqkv_p = (float*)alloc((size_t)4 * 1152 * 4);
  float* bo_p   = (float*)alloc((size_t)4 * 384 * 4);
  float* bf1_p  = (float*)alloc((size_t)4 * 1408 * 4);
  float* bf2_p  = (float*)alloc((size_t)4 * 384 * 4);

  const size_t fixed = off;
  int NC = 1;
  while (NC < 16 && fixed + (size_t)(M / NC) * 2304 + (1u << 20) > ws_size) NC <<= 1;
  const long Mc = M / NC;
  const long Mc2 = Mc / 2;
  const long sec = Mc * 48;

  char* R = alloc((size_t)Mc * 2304);
  short* qkv_bf = (short*)R;                              // [24][Mc][48] head-major
  short* f_bf   = (short*)R;                              // [Mc2][1344] (subchunk)
  short* x_bfc  = (short*)R;                              // [Mc][96]

  const dim3 blk(256);

  auto conv_w = [&](const float* s, short* d, int N, int K, int Np, int Kp, int L) {
    const int total = L * Np * Kp;
    conv_w_kernel<<<dim3((total + 255) / 256), blk, 0, stream>>>(s, d, N, K, Np, Kp, total);
  };
  auto conv_b = [&](const float* s, float* d, int N, int Np, int L) {
    const int total = L * Np;
    conv_b_kernel<<<dim3((total + 255) / 256), blk, 0, stream>>>(s, d, N, Np, total);
  };
  conv_w(Wp,  Wp_b,  288,   83, 384,   96, 1);
  conv_wqkv_kernel<<<dim3((4 * 1152 * 288 + 255) / 256), blk, 0, stream>>>(Wq, Wk, Wv, temp, Wqkv_b);
  conv_wo_kernel<<<dim3((4 * 288 * 384 + 255) / 256), blk, 0, stream>>>(Wo, Wo_b);
  conv_w(Wf1, Wf1_b, 1315, 288, 1408, 288, 4);
  conv_w(Wf2, Wf2_b, 288, 1315, 384, 1344, 4);
  conv_b(bp,  bp_p,  288,  384, 1);
  conv_bqkv_kernel<<<dim3((4 * 1152 + 255) / 256), blk, 0, stream>>>(bq, bk, bv, temp, bqkv_p);
  conv_b(bo,  bo_p,  288,  384, 4);
  conv_b(bf1, bf1_p, 1315, 1408, 4);
  conv_b(bf2, bf2_p, 288,  384, 4);
  pe_kernel<<<dim3((128 * 384 + 255) / 256), blk, 0, stream>>>(phase, pe_mod);

  auto gemm = [&](int mode, const short* A, const short* Bmat, const float* bias,
                  short* C, const float* pe, int K, int lda, int ldb, int ldc,
                  int Nstore, int NT, long Mrows, long hstride) {
    const dim3 grid((unsigned)((Mrows / 128) * NT));
    switch (mode) {
      case 0: gemm_kernel<0><<<grid, blk, 0, stream>>>(A, Bmat, bias, C, pe, K, lda, ldb, ldc, Nstore, NT, hstride); break;
      case 1: gemm_kernel<1><<<grid, blk, 0, stream>>>(A, Bmat, bias, C, pe, K, lda, ldb, ldc, Nstore, NT, hstride); break;
      case 2: gemm_kernel<2><<<grid, blk, 0, stream>>>(A, Bmat, bias, C, pe, K, lda, ldb, ldc, Nstore, NT, hstride); break;
      default: gemm_kernel<3><<<grid, blk, 0, stream>>>(A, Bmat, bias, C, pe, K, lda, ldb, ldc, Nstore, NT, hstride); break;
    }
  };

  for (int c = 0; c < NC; ++c) {
    const float* x_c = x + (size_t)c * Mc * 83;
    short* h_c = h_bf + (size_t)c * Mc * 288;

    const int xtot = (int)(Mc * 96);
    conv_x_kernel<<<dim3((xtot + 255) / 256), blk, 0, stream>>>(x_c, x_bfc, xtot);

    gemm(2, x_bfc, Wp_b, bp_p, h_c, pe_mod, 96, 96, 96, 288, 288, 3, Mc, 0);

    for (int l = 0; l < 4; ++l) {
      const short* Wqkv_l = Wqkv_b + (size_t)l * 1152 * 288;
      const short* Wo_l   = Wo_b   + (size_t)l * 288 * 384;
      const short* Wf1_l  = Wf1_b  + (size_t)l * 1408 * 288;
      const short* Wf2_l  = Wf2_b  + (size_t)l * 384 * 1344;

      gemm(3, h_c, Wqkv_l, bqkv_p + l * 1152, qkv_bf, nullptr,
           288, 288, 288, 0, 1152, 9, Mc, sec);

      attn_kernel<<<dim3((unsigned)(Mc / 128), 8), blk, 0, stream>>>(
          qkv_bf, qscale, l, Mc);

      gemm_ln_kernel<true><<<dim3((unsigned)(Mc / 128)), dim3(512), 0, stream>>>(
          qkv_bf + 16 * sec, Wo_l, bo_p + l * 384, h_c, n1w + l * 288, n1b + l * 288,
          skip, l, 1, 384, 48, 384, sec);

      for (int s = 0; s < 2; ++s) {
        short* h_s = h_c + (size_t)s * Mc2 * 288;
        gemm(1, h_s, Wf1_l, bf1_p + l * 1408, f_bf, nullptr,
             288, 288, 288, 1344, 1344, 11, Mc2, 0);
        gemm_ln_kernel<false><<<dim3((unsigned)(Mc2 / 128)), dim3(512), 0, stream>>>(
            f_bf, Wf2_l, bf2_p + l * 384, h_s, n2w + l * 288, n2b + l * 288,
            skip, l, 0, 1344, 1344, 1344, 0);
      }
    }
  }

  head_kernel<<<dim3(1024), blk, 0, stream>>>(h_bf, (float*)d_out,
      bn_w, bn_b, bn_mean, bn_var,
      h1w, h1b, h2w, h2b, h3w, h3b,
      u1w, u1b, u2w, u2b);
}